// Round 6
// baseline (561.128 us; speedup 1.0000x reference)
//
#include <hip/hip_runtime.h>

// SignalingModel: X_{t+1} = mml(W @ X_t + X_bias), 60 steps, W 0.24% sparse.
// R3: edge structure staged into LDS (slot-major, conflict-free b64 reads),
// 1024 threads/block, 2 samples/block (grid=256, 16 waves/CU), entries
// prefetched to registers per step, segmented-run scatter via LDS atomicAdd.
// Rationale: R1/R2 VGPR counts (36/76) prove the compiler never kept the edge
// arrays register-resident -> per-step global reloads were the bottleneck.

#define NN 2048
#define STEPS 60
#define LEAKV 0.01f
#define EMAX 10240          // E; actual nnz <= EMAX
#define TPB 1024
#define EPT 10              // EMAX / TPB consecutive sorted edges per thread
#define SPB 2               // samples per block
#define LDS_PAIR_BYTES (EMAX * 8)                 // 81920
#define LDS_TOTAL (LDS_PAIR_BYTES + SPB * 2 * NN * 4)  // 114688 (112 KB)

__device__ __forceinline__ float mml_f(float x) {
  if (x < 0.0f)      return LEAKV * x;
  else if (x < 0.5f) return x;
  else               return 1.0f - 0.25f / x;
}

// --- build pipeline (edges sorted by (tgt,src) row-major scan of W) -------

__global__ __launch_bounds__(64) void count_row(const float* __restrict__ W,
                                                int* __restrict__ cnt) {
  const int n = blockIdx.x, lane = threadIdx.x;
  int c = 0;
  for (int c0 = 0; c0 < NN; c0 += 64) {
    float w = W[n * NN + c0 + lane];
    c += __popcll(__ballot(w != 0.0f));
  }
  if (lane == 0) cnt[n] = c;
}

__global__ __launch_bounds__(1024) void scan2048(const int* __restrict__ cnt,
                                                 int* __restrict__ base) {
  __shared__ int sb[2][NN];
  const int t = threadIdx.x;
  sb[0][t] = cnt[t];
  sb[0][t + 1024] = cnt[t + 1024];
  __syncthreads();
  int p = 0;
  for (int off = 1; off < NN; off <<= 1) {
    int i0 = t, i1 = t + 1024;
    sb[p ^ 1][i0] = sb[p][i0] + (i0 >= off ? sb[p][i0 - off] : 0);
    sb[p ^ 1][i1] = sb[p][i1] + (i1 >= off ? sb[p][i1 - off] : 0);
    __syncthreads();
    p ^= 1;
  }
  base[t] = sb[p][t] - cnt[t];
  base[t + 1024] = sb[p][t + 1024] - cnt[t + 1024];
}

__global__ __launch_bounds__(64) void fill_edges(const float* __restrict__ W,
                                                 const int* __restrict__ base,
                                                 uint2* __restrict__ pg) {
  const int n = blockIdx.x, lane = threadIdx.x;
  const int b = base[n];
  int off = 0;
  for (int c0 = 0; c0 < NN; c0 += 64) {
    float w = W[n * NN + c0 + lane];
    unsigned long long m = __ballot(w != 0.0f);
    if (w != 0.0f) {
      int e = b + off + __popcll(m & ((1ull << lane) - 1ull));
      pg[e] = make_uint2(__float_as_uint(w),
                         ((unsigned)n << 16) | (unsigned)(c0 + lane));
    }
    off += __popcll(m);
  }
}

// --- simulation -----------------------------------------------------------

__global__ __launch_bounds__(TPB, 4) void sim(const float* __restrict__ Xfull,
                                              const float* __restrict__ bias,
                                              const uint2* __restrict__ pg,
                                              float* __restrict__ out) {
  extern __shared__ char smem[];
  uint2* pr = (uint2*)smem;                       // [EPT][TPB] slot-major
  float* Xs = (float*)(smem + LDS_PAIR_BYTES);    // [SPB][2][NN]

  const int t = (int)threadIdx.x;
  const int s0 = (int)blockIdx.x * SPB;

  // stage edges: coalesced global b64 read -> slot-major LDS (one-time)
#pragma unroll
  for (int i = 0; i < EPT; ++i) {
    const int e = i * TPB + t;
    pr[(e % EPT) * TPB + (e / EPT)] = pg[e];
  }

  // thread owns nodes {2t, 2t+1}; per-sample xb in regs
  float2 xb0, xb1;
  {
    const float2 bv = *(const float2*)&bias[2 * t];
    float2 a = *(const float2*)&Xfull[(size_t)s0 * NN + 2 * t];
    float2 c = *(const float2*)&Xfull[(size_t)(s0 + 1) * NN + 2 * t];
    xb0 = make_float2(a.x + bv.x, a.y + bv.y);
    xb1 = make_float2(c.x + bv.x, c.y + bv.y);
    float* X0 = Xs;              // sample 0: [2][NN]
    float* X1 = Xs + 2 * NN;     // sample 1: [2][NN]
    *(float2*)&X0[2 * t]      = make_float2(mml_f(xb0.x), mml_f(xb0.y)); // X1=mml(xb)
    *(float2*)&X0[NN + 2 * t] = xb0;                                     // acc preinit
    *(float2*)&X1[2 * t]      = make_float2(mml_f(xb1.x), mml_f(xb1.y));
    *(float2*)&X1[NN + 2 * t] = xb1;
  }
  __syncthreads();

  float* X0 = Xs;
  float* X1 = Xs + 2 * NN;
  int cur = 0;
  for (int it = 0; it < STEPS - 1; ++it) {   // produces X2..X60
    const float* a0 = X0 + cur * NN;
    float*       n0 = X0 + (cur ^ 1) * NN;
    const float* a1 = X1 + cur * NN;
    float*       n1 = X1 + (cur ^ 1) * NN;

    // prefetch this thread's 10 entries (conflict-free b64, compile-time idx)
    uint2 e[EPT];
#pragma unroll
    for (int k = 0; k < EPT; ++k) e[k] = pr[k * TPB + t];

    float r0 = 0.0f, r1 = 0.0f;
#pragma unroll
    for (int k = 0; k < EPT; ++k) {
      const float w   = __uint_as_float(e[k].x);
      const int   src = (int)(e[k].y & 0xffffu);
      const int   tgt = (int)(e[k].y >> 16);
      r0 += w * a0[src];
      r1 += w * a1[src];
      const bool end = (k == EPT - 1) || ((e[k + (k < EPT - 1)].y >> 16) != (e[k].y >> 16));
      if (end) {
        atomicAdd(&n0[tgt], r0);
        atomicAdd(&n1[tgt], r1);
        r0 = 0.0f; r1 = 0.0f;
      }
    }
    __syncthreads();

    // finalize next state + reinit consumed buffer
    {
      float2 v0 = *(float2*)&n0[2 * t];
      float2 v1 = *(float2*)&n1[2 * t];
      *(float2*)&n0[2 * t] = make_float2(mml_f(v0.x), mml_f(v0.y));
      *(float2*)&n1[2 * t] = make_float2(mml_f(v1.x), mml_f(v1.y));
      *(float2*)&((float*)(X0 + cur * NN))[2 * t] = xb0;
      *(float2*)&((float*)(X1 + cur * NN))[2 * t] = xb1;
    }
    __syncthreads();
    cur ^= 1;
  }

  *(float2*)&out[(size_t)s0 * NN + 2 * t]       = *(float2*)&(X0 + cur * NN)[2 * t];
  *(float2*)&out[(size_t)(s0 + 1) * NN + 2 * t] = *(float2*)&(X1 + cur * NN)[2 * t];
}

extern "C" void kernel_launch(void* const* d_in, const int* in_sizes, int n_in,
                              void* d_out, int out_size, void* d_ws, size_t ws_size,
                              hipStream_t stream) {
  const float* Xfull = (const float*)d_in[0];   // (B, N) f32
  const float* W     = (const float*)d_in[1];   // (N, N) f32
  const float* bias  = (const float*)d_in[2];   // (N, 1) f32
  float* out = (float*)d_out;

  // ws: pg[EMAX] uint2 (80KB) | cnt[NN] i32 | base[NN] i32
  char* ws = (char*)d_ws;
  uint2* pg = (uint2*)ws;
  int* cnt  = (int*)(ws + (size_t)EMAX * 8);
  int* base = (int*)(ws + (size_t)EMAX * 8 + (size_t)NN * 4);

  const int B = in_sizes[0] / NN;   // 512

  hipFuncSetAttribute((const void*)sim,
                      hipFuncAttributeMaxDynamicSharedMemorySize, LDS_TOTAL);

  // zero-pad edges (padding: w=0, tgt=src=0 -> contributes exact +0.0)
  hipMemsetAsync(pg, 0, (size_t)EMAX * 8, stream);
  count_row<<<NN, 64, 0, stream>>>(W, cnt);
  scan2048<<<1, 1024, 0, stream>>>(cnt, base);
  fill_edges<<<NN, 64, 0, stream>>>(W, base, pg);
  sim<<<B / SPB, TPB, LDS_TOTAL, stream>>>(Xfull, bias, pg, out);
}